// Round 4
// baseline (294.431 us; speedup 1.0000x reference)
//
#include <hip/hip_runtime.h>
#include <hip/hip_bf16.h>
#include <stdint.h>

typedef __bf16 bf16_t;
typedef __bf16 bf16x8 __attribute__((ext_vector_type(8)));
typedef float  f32x4  __attribute__((ext_vector_type(4)));

#define MFMA(a, b, c) __builtin_amdgcn_mfma_f32_16x16x32_bf16((a), (b), (c), 0, 0, 0)

// ---------------------------------------------------------------- K1: linears
__global__ __launch_bounds__(128) void k_linear(
    const float* __restrict__ h, const float* __restrict__ Wi,
    const float* __restrict__ bi, const float* __restrict__ Wj,
    const float* __restrict__ bj, bf16_t* __restrict__ ui,
    bf16_t* __restrict__ vj) {
  int bl = blockIdx.x;
  int which = blockIdx.y;
  const float* W = which ? Wj : Wi;
  const float* bias = which ? bj : bi;
  bf16_t* out = which ? vj : ui;
  __shared__ float hrow[1024];
  for (int i = threadIdx.x; i < 1024; i += 128) hrow[i] = h[bl * 1024 + i];
  __syncthreads();
  int p = threadIdx.x;
  const float* w = W + (size_t)p * 1024;
  float acc = bias[p];
  for (int i = 0; i < 1024; i += 4) {
    f32x4 wv = *(const f32x4*)(w + i);
    acc += hrow[i] * wv[0] + hrow[i + 1] * wv[1] + hrow[i + 2] * wv[2] +
           hrow[i + 3] * wv[3];
  }
  out[bl * 128 + p] = (bf16_t)acc;
}

// ------------------------------------------------- K2a: W[i][j][k]->Wt[k][j][i]
__global__ __launch_bounds__(256) void k_wt(const float* __restrict__ W,
                                            bf16_t* __restrict__ Wt) {
  int j = blockIdx.x;
  int i0 = blockIdx.y * 32, k0 = blockIdx.z * 32;
  __shared__ float tile[32][33];
  int tx = threadIdx.x & 31, ty = threadIdx.x >> 5;  // ty 0..7
#pragma unroll
  for (int r = 0; r < 4; r++) {
    int ii = ty + r * 8;
    tile[ii][tx] = W[(size_t)(i0 + ii) * 16384 + j * 128 + (k0 + tx)];
  }
  __syncthreads();
#pragma unroll
  for (int r = 0; r < 4; r++) {
    int kk = ty + r * 8;
    Wt[(size_t)(k0 + kk) * 16384 + j * 128 + (i0 + tx)] = (bf16_t)tile[tx][kk];
  }
}

// -------- K2b: mix_w[oc][ic][tap] -> Wc2 in MFMA-fragment order
// Wc2[tap][wrh][kc][fm][ln][e]: oc=wrh*64+fm*16+(ln&15), ic=kc*32+(ln>>4)*8+e
__global__ __launch_bounds__(256) void k_wc(const float* __restrict__ mw,
                                            bf16_t* __restrict__ Wc2) {
  int idx = blockIdx.x * 256 + threadIdx.x;
  if (idx < 147456) {
    int e = idx & 7, ln = (idx >> 3) & 63, fm = (idx >> 9) & 3;
    int kc = (idx >> 11) & 3, wrh = (idx >> 13) & 1, tap = idx >> 14;
    int oc = wrh * 64 + fm * 16 + (ln & 15);
    int ic = kc * 32 + (ln >> 4) * 8 + e;
    Wc2[idx] = (bf16_t)mw[oc * 1152 + ic * 9 + tap];
  }
}

// -------- K2c: out_w -> Wo2 in MFMA-fragment order [wrh][kc][fm][ln][e]
__global__ __launch_bounds__(256) void k_wo(const float* __restrict__ ow,
                                            bf16_t* __restrict__ Wo2) {
  int idx = blockIdx.x * 256 + threadIdx.x;
  if (idx < 16384) {
    int e = idx & 7, ln = (idx >> 3) & 63, fm = (idx >> 9) & 3;
    int kc = (idx >> 11) & 3, wrh = (idx >> 13) & 1;
    int oc2 = wrh * 64 + fm * 16 + (ln & 15);
    int mc = kc * 32 + (ln >> 4) * 8 + e;
    Wo2[idx] = (bf16_t)ow[oc2 * 128 + mc];
  }
}

// ------------------- K3: t[bl][k*128+j] = sum_i ui[bl][i] * Wt[k][j][i]  (GEMM)
__global__ __launch_bounds__(256) void k_tgemm(const bf16_t* __restrict__ A,
                                               const bf16_t* __restrict__ Bt,
                                               bf16_t* __restrict__ T) {
  int m0 = blockIdx.x * 64;  // bl
  int n0 = blockIdx.y * 64;  // (k,j)
  __shared__ bf16_t Al[64][136], Bl[64][136];
  for (int c = threadIdx.x; c < 64 * 16; c += 256) {
    int row = c >> 4, col = (c & 15) * 8;
    *(uint4*)&Al[row][col] = *(const uint4*)&A[(size_t)(m0 + row) * 128 + col];
    *(uint4*)&Bl[row][col] = *(const uint4*)&Bt[(size_t)(n0 + row) * 128 + col];
  }
  __syncthreads();
  int w = threadIdx.x >> 6, ln = threadIdx.x & 63;
  int wr = (w >> 1) * 32, wc = (w & 1) * 32;
  int lr = ln & 15, hi8 = (ln >> 4) * 8, rb = (ln >> 4) * 4;
  f32x4 acc[2][2] = {};
#pragma unroll
  for (int kc = 0; kc < 128; kc += 32) {
    bf16x8 a0 = *(bf16x8*)&Al[wr + lr][kc + hi8];
    bf16x8 a1 = *(bf16x8*)&Al[wr + 16 + lr][kc + hi8];
    bf16x8 b0 = *(bf16x8*)&Bl[wc + lr][kc + hi8];
    bf16x8 b1 = *(bf16x8*)&Bl[wc + 16 + lr][kc + hi8];
    acc[0][0] = MFMA(a0, b0, acc[0][0]);
    acc[0][1] = MFMA(a0, b1, acc[0][1]);
    acc[1][0] = MFMA(a1, b0, acc[1][0]);
    acc[1][1] = MFMA(a1, b1, acc[1][1]);
  }
#pragma unroll
  for (int fm = 0; fm < 2; fm++)
#pragma unroll
    for (int fn = 0; fn < 2; fn++) {
      int col = n0 + wc + fn * 16 + lr;
#pragma unroll
      for (int r = 0; r < 4; r++) {
        int row = m0 + wr + fm * 16 + rb + r;
        T[(size_t)row * 16384 + col] = (bf16_t)acc[fm][fn][r];
      }
    }
}

// ------- K4: feat[b][l][m][k] = sum_j t[bl][k][j] * vj[b][m][j]
// LDS-bounce for coalesced F writes; fused deterministic norm partial sums.
__global__ __launch_bounds__(256) void k_feat(const bf16_t* __restrict__ T,
                                              const bf16_t* __restrict__ Vb,
                                              bf16_t* __restrict__ F,
                                              float* __restrict__ part) {
  int bl = blockIdx.x;
  int b = bl / 384;
  __shared__ __align__(16) char sm[69632];
  bf16_t (*Tl)[136] = (bf16_t(*)[136])(sm);            // 34816
  bf16_t (*Vm)[136] = (bf16_t(*)[136])(sm + 34816);    // 17408
  bf16_t (*Fb)[136] = (bf16_t(*)[136])(sm + 52224);    // 17408
  float* rs = (float*)(sm);                            // overlay after loop
  float* rq = (float*)(sm + 8192);
  const bf16_t* tsrc = T + (size_t)bl * 16384;
  for (int c = threadIdx.x; c < 128 * 16; c += 256) {
    int row = c >> 4, col = (c & 15) * 8;
    *(uint4*)&Tl[row][col] = *(const uint4*)&tsrc[row * 128 + col];
  }
  int w = threadIdx.x >> 6, ln = threadIdx.x & 63;
  int wr = (w >> 1) * 64, wc = (w & 1) * 32;
  int lr = ln & 15, hi8 = (ln >> 4) * 8, rb = (ln >> 4) * 4;
  size_t base = (size_t)bl * 384 * 128;
  float s8[8] = {}, q8[8] = {};
  int col8 = threadIdx.x & 15;
  for (int mt = 0; mt < 6; mt++) {
    __syncthreads();
    for (int c = threadIdx.x; c < 64 * 16; c += 256) {
      int row = c >> 4, col = (c & 15) * 8;
      *(uint4*)&Vm[row][col] =
          *(const uint4*)&Vb[(size_t)(b * 384 + mt * 64 + row) * 128 + col];
    }
    __syncthreads();
    f32x4 acc[4][2] = {};
#pragma unroll
    for (int kc = 0; kc < 128; kc += 32) {
      bf16x8 b0 = *(bf16x8*)&Vm[wc + lr][kc + hi8];
      bf16x8 b1 = *(bf16x8*)&Vm[wc + 16 + lr][kc + hi8];
#pragma unroll
      for (int fm = 0; fm < 4; fm++) {
        bf16x8 av = *(bf16x8*)&Tl[wr + fm * 16 + lr][kc + hi8];
        acc[fm][0] = MFMA(av, b0, acc[fm][0]);
        acc[fm][1] = MFMA(av, b1, acc[fm][1]);
      }
    }
    union {
      bf16_t h[4];
      uint2 u;
    } pk;
#pragma unroll
    for (int fm = 0; fm < 4; fm++)
#pragma unroll
      for (int fn = 0; fn < 2; fn++) {
        int m = wc + fn * 16 + lr;
        int kb = wr + fm * 16 + rb;
#pragma unroll
        for (int r = 0; r < 4; r++) pk.h[r] = (bf16_t)acc[fm][fn][r];
        *(uint2*)&Fb[m][kb] = pk.u;
      }
    __syncthreads();
    // coalesced copy-out + stats accumulation
    for (int c = threadIdx.x; c < 64 * 16; c += 256) {
      int row = c >> 4;
      uint4 v = *(uint4*)&Fb[row][col8 * 8];
      *(uint4*)&F[base + (size_t)(mt * 64 + row) * 128 + col8 * 8] = v;
      const bf16_t* hp = (const bf16_t*)&v;
#pragma unroll
      for (int e = 0; e < 8; e++) {
        float f = (float)hp[e];
        s8[e] += f;
        q8[e] += f * f;
      }
    }
  }
  // deterministic block reduction over the 16 row-groups
  int sub = threadIdx.x >> 4;
#pragma unroll
  for (int e = 0; e < 8; e++) {
    rs[(sub * 16 + col8) * 8 + e] = s8[e];
    rq[(sub * 16 + col8) * 8 + e] = q8[e];
  }
  __syncthreads();
  if (threadIdx.x < 128) {
    int k = threadIdx.x, kg = k >> 3, e = k & 7;
    float S = 0.f, Q = 0.f;
#pragma unroll
    for (int s = 0; s < 16; s++) {
      S += rs[(s * 16 + kg) * 8 + e];
      Q += rq[(s * 16 + kg) * 8 + e];
    }
    part[(size_t)bl * 256 + k] = S;
    part[(size_t)bl * 256 + 128 + k] = Q;
  }
}

// ----------------------------------------- K5: finalize scale/shift per (b,k)
__global__ __launch_bounds__(64) void k_stats2(const float* __restrict__ part,
                                               const float* __restrict__ gamma,
                                               const float* __restrict__ beta,
                                               float* __restrict__ ss) {
  int k = blockIdx.x, b = blockIdx.y, t = threadIdx.x;
  float S = 0.f, Q = 0.f;
  for (int l = t; l < 384; l += 64) {
    S += part[(size_t)(b * 384 + l) * 256 + k];
    Q += part[(size_t)(b * 384 + l) * 256 + 128 + k];
  }
#pragma unroll
  for (int o = 32; o; o >>= 1) {
    S += __shfl_down(S, o, 64);
    Q += __shfl_down(Q, o, 64);
  }
  if (t == 0) {
    const float inv = 1.0f / 147456.0f;
    float mean = S * inv;
    float var = Q * inv - mean * mean;
    float sc = gamma[k] * rsqrtf(var + 1e-5f);
    ss[(b * 128 + k) * 2] = sc;
    ss[(b * 128 + k) * 2 + 1] = beta[k] - mean * sc;
  }
}

// --- K7: fused norm+relu -> conv3x3 -> relu -> conv1x1 + bias
// 2 waves/block (128 thr), wave = 64oc x 128px (acc 4x8).
// A (weights) global->VGPR per fragment (no LDS); B in LDS, 256B stride,
// XOR swizzle byte^=(row&7)<<4 on write and read (G4 measured recipe).
__global__ __launch_bounds__(128, 2) void k_conv(
    const bf16_t* __restrict__ F, const float* __restrict__ ss,
    const bf16_t* __restrict__ Wc2, const bf16_t* __restrict__ Wo2,
    const float* __restrict__ outb, float* __restrict__ out) {
  int orig = blockIdx.x;
  int wg = (orig & 7) * 288 + (orig >> 3);  // 2304 % 8 == 0: bijective
  int xt = wg % 3;
  int t1 = wg / 3;
  int b = t1 / 384;
  int y = t1 - b * 384;
  int x0 = xt * 128;

  __shared__ __align__(16) char sm[34304];
  // [0,33280): Bsl 130 rows x 256B (swizzled); epilogue: Mx 128 x 256B
  // [33280,34304): ssc/ssh
  float* ssc = (float*)(sm + 33280);
  float* ssh = ssc + 128;

  int tid = threadIdx.x;
  if (tid < 128) {
    ssc[tid] = ss[(b * 128 + tid) * 2];
    ssh[tid] = ss[(b * 128 + tid) * 2 + 1];
  }

  int w = tid >> 6, ln = tid & 63;
  int lr = ln & 15, g = ln >> 4;
  int hi8 = g * 8, rb = g * 4;

  f32x4 acc[4][8] = {};
  for (int dy = 0; dy < 3; dy++) {
    int yy = y + dy - 1;
    bool yok = (yy >= 0 && yy < 384);
    __syncthreads();  // prev-dy Bsl reads done; dy=0: ssc ready
    const bf16_t* Frow = F + (size_t)(b * 384 + yy) * 384 * 128;
    for (int idx = tid; idx < 130 * 16; idx += 128) {
      int px = idx >> 4, c8 = (idx & 15) << 3;
      int xx = x0 - 1 + px;
      bf16x8 o;
      if (yok && xx >= 0 && xx < 384) {
        bf16x8 f = *(const bf16x8*)&Frow[(size_t)xx * 128 + c8];
#pragma unroll
        for (int e = 0; e < 8; e++) {
          float v = (float)f[e] * ssc[c8 + e] + ssh[c8 + e];
          o[e] = (bf16_t)(v > 0.f ? v : 0.f);
        }
      } else {
#pragma unroll
        for (int e = 0; e < 8; e++) o[e] = (bf16_t)0.f;
      }
      int byte = (px << 8) + (c8 << 1);
      *(bf16x8*)(sm + (byte ^ ((px & 7) << 4))) = o;
    }
    __syncthreads();  // Bsl ready
#pragma unroll 1
    for (int dx = 0; dx < 3; dx++) {
      const bf16_t* Atap =
          Wc2 + (size_t)(dy * 3 + dx) * 16384 + w * 8192 + ln * 8;
      // preload all 16 A fragments of this tap (global -> VGPR, coalesced 1KB)
      bf16x8 av[16];
#pragma unroll
      for (int kc = 0; kc < 4; kc++)
#pragma unroll
        for (int fm = 0; fm < 4; fm++)
          av[kc * 4 + fm] = *(const bf16x8*)&Atap[kc * 2048 + fm * 512];
#pragma unroll
      for (int kc = 0; kc < 4; kc++) {
        bf16x8 bv[8];
#pragma unroll
        for (int fn = 0; fn < 8; fn++) {
          int row = fn * 16 + lr + dx;
          int byte = (row << 8) + (kc << 6) + (g << 4);
          bv[fn] = *(const bf16x8*)(sm + (byte ^ ((row & 7) << 4)));
        }
#pragma unroll
        for (int fm = 0; fm < 4; fm++)
#pragma unroll
          for (int fn = 0; fn < 8; fn++)
            acc[fm][fn] = MFMA(av[kc * 4 + fm], bv[fn], acc[fm][fn]);
      }
    }
  }
  // ---- epilogue: relu(mix)->Mx (swizzled, overlays Bsl), 1x1 GEMM + bias
  __syncthreads();  // all Bsl reads done
  union {
    bf16_t h[4];
    uint2 u;
  } pk;
#pragma unroll
  for (int fm = 0; fm < 4; fm++)
#pragma unroll
    for (int fn = 0; fn < 8; fn++) {
      int px = fn * 16 + lr;
      int mcb = w * 64 + fm * 16 + rb;
#pragma unroll
      for (int r = 0; r < 4; r++) {
        float v = acc[fm][fn][r];
        pk.h[r] = (bf16_t)(v > 0.f ? v : 0.f);
      }
      int byte = (px << 8) + (mcb << 1);
      *(uint2*)(sm + (byte ^ ((px & 7) << 4))) = pk.u;
    }
  __syncthreads();  // Mx ready
  f32x4 acc2[4][8] = {};
  const bf16_t* Awo = Wo2 + w * 8192 + ln * 8;
#pragma unroll
  for (int kc = 0; kc < 4; kc++) {
    bf16x8 av2[4];
#pragma unroll
    for (int fm = 0; fm < 4; fm++)
      av2[fm] = *(const bf16x8*)&Awo[kc * 2048 + fm * 512];
    bf16x8 bv[8];
#pragma unroll
    for (int fn = 0; fn < 8; fn++) {
      int row = fn * 16 + lr;
      int byte = (row << 8) + (kc << 6) + (g << 4);
      bv[fn] = *(const bf16x8*)(sm + (byte ^ ((row & 7) << 4)));
    }
#pragma unroll
    for (int fm = 0; fm < 4; fm++)
#pragma unroll
      for (int fn = 0; fn < 8; fn++)
        acc2[fm][fn] = MFMA(av2[fm], bv[fn], acc2[fm][fn]);
  }
  f32x4 obv[4];
#pragma unroll
  for (int fm = 0; fm < 4; fm++)
    obv[fm] = *(const f32x4*)&outb[w * 64 + fm * 16 + rb];
#pragma unroll
  for (int fm = 0; fm < 4; fm++)
#pragma unroll
    for (int fn = 0; fn < 8; fn++) {
      int x = x0 + fn * 16 + lr;
#pragma unroll
      for (int r = 0; r < 4; r++) {
        int oc2 = w * 64 + fm * 16 + rb + r;
        out[((size_t)(b * 128 + oc2) * 384 + y) * 384 + x] =
            acc2[fm][fn][r] + obv[fm][r];
      }
    }
}

extern "C" void kernel_launch(void* const* d_in, const int* in_sizes, int n_in,
                              void* d_out, int out_size, void* d_ws,
                              size_t ws_size, hipStream_t stream) {
  const float* h = (const float*)d_in[0];
  const float* Wi = (const float*)d_in[1];
  const float* bi = (const float*)d_in[2];
  const float* Wj = (const float*)d_in[3];
  const float* bj = (const float*)d_in[4];
  const float* Wbl = (const float*)d_in[5];
  const float* gamma = (const float*)d_in[6];
  const float* beta = (const float*)d_in[7];
  const float* mw = (const float*)d_in[8];
  const float* ow = (const float*)d_in[9];
  const float* ob = (const float*)d_in[10];
  float* out = (float*)d_out;

  char* ws = (char*)d_ws;
  size_t off = 0;
  auto alloc = [&](size_t bytes) -> void* {
    void* p = ws + off;
    off = (off + bytes + 255) & ~(size_t)255;
    return p;
  };
  bf16_t* ui_b = (bf16_t*)alloc(768 * 128 * 2);
  bf16_t* vj_b = (bf16_t*)alloc(768 * 128 * 2);
  bf16_t* Wt = (bf16_t*)alloc((size_t)2097152 * 2);
  bf16_t* Wc2 = (bf16_t*)alloc((size_t)147456 * 2);
  bf16_t* Wo2 = (bf16_t*)alloc((size_t)16384 * 2);
  bf16_t* T = (bf16_t*)alloc((size_t)768 * 16384 * 2);
  bf16_t* F = (bf16_t*)alloc((size_t)2 * 384 * 384 * 128 * 2);
  float* part = (float*)alloc((size_t)768 * 256 * 4);
  float* ssb = (float*)alloc((size_t)2 * 128 * 2 * 4);

  k_linear<<<dim3(768, 2), 128, 0, stream>>>(h, Wi, bi, Wj, bj, ui_b, vj_b);
  k_wt<<<dim3(128, 4, 4), 256, 0, stream>>>(Wbl, Wt);
  k_wc<<<(147456 + 255) / 256, 256, 0, stream>>>(mw, Wc2);
  k_wo<<<64, 256, 0, stream>>>(ow, Wo2);
  k_tgemm<<<dim3(12, 256), 256, 0, stream>>>(ui_b, Wt, T);
  k_feat<<<768, 256, 0, stream>>>(T, vj_b, F, part);
  k_stats2<<<dim3(128, 2), 64, 0, stream>>>(part, gamma, beta, ssb);
  k_conv<<<2304, 128, 0, stream>>>(F, ssb, Wc2, Wo2, ob, out);
}